// Round 13
// baseline (218.004 us; speedup 1.0000x reference)
//
#include <hip/hip_runtime.h>
#include <hip/hip_bf16.h>
#include <stdint.h>

#define HEADS 8
#define DHEAD 64
#define DIM 512
#define NSEQ 2048
#define BATCH 2
#define NROWS (BATCH * NSEQ)      // 4096
#define QKV_N 1536
#define REL_ROWS 1025
#define REL_PITCH_ROWS 1088
#define NSPLIT 2
#define KV_PER_SPLIT (NSEQ / NSPLIT)   // 1024

static constexpr float SCALE_LOG2E = 0.125f * 1.4426950408889634f;  // SCALE * log2(e)

typedef __attribute__((ext_vector_type(8))) short bf16x8;   // 8 bf16 (4 VGPRs)
typedef __attribute__((ext_vector_type(4))) float f32x4;

__device__ __forceinline__ uint16_t f2bf(float f) {
    union { float f; uint32_t u; } v{f};
    uint32_t r = (v.u + 0x7FFFu + ((v.u >> 16) & 1u)) >> 16;
    return (uint16_t)r;
}

// ---------------------------------------------------------------- prep (merged): x->bf16, rel->bf16, W transposes
__global__ void prep_all(const float* __restrict__ x, const float* __restrict__ rel,
                         const float* __restrict__ Wq, const float* __restrict__ Wkv,
                         const float* __restrict__ Wo,
                         uint16_t* __restrict__ xb, uint16_t* __restrict__ relb,
                         uint16_t* __restrict__ Wqkv_t, uint16_t* __restrict__ Wo_t) {
    if (blockIdx.x < 2048) {
        int total = NROWS * DIM + REL_PITCH_ROWS * DHEAD;
        for (int idx = blockIdx.x * blockDim.x + threadIdx.x; idx < total; idx += 2048 * blockDim.x) {
            if (idx < NROWS * DIM) {
                xb[idx] = f2bf(x[idx]);
            } else {
                int i2 = idx - NROWS * DIM;
                relb[i2] = (i2 < REL_ROWS * DHEAD) ? f2bf(rel[i2]) : (uint16_t)0;
            }
        }
        return;
    }
    __shared__ float tile[32][33];
    int bid = blockIdx.x - 2048;
    const float* src; uint16_t* dst; int J, ti, tj;
    if (bid < 256)      { src = Wq;  dst = Wqkv_t;             J = 512;  ti = bid >> 4;        tj = bid & 15; }
    else if (bid < 768) { int b = bid - 256; src = Wkv; dst = Wqkv_t + 512 * 512; J = 1024; ti = b >> 5; tj = b & 31; }
    else                { int b = bid - 768; src = Wo;  dst = Wo_t;   J = 512;  ti = b >> 4;        tj = b & 15; }
    int tx = threadIdx.x & 31, ty = threadIdx.x >> 5;
    int k0 = ti * 32, j0 = tj * 32;
    #pragma unroll
    for (int i = 0; i < 4; i++) tile[ty + 8 * i][tx] = src[(size_t)(k0 + ty + 8 * i) * J + j0 + tx];
    __syncthreads();
    #pragma unroll
    for (int i = 0; i < 4; i++) dst[(size_t)(j0 + ty + 8 * i) * 512 + k0 + tx] = f2bf(tile[tx][ty + 8 * i]);
}

// ---------------------------------------------------------------- 128x128 MFMA GEMM: C = A[M,K] * Bt[N,K]^T
template <bool BF16_OUT>
__global__ __launch_bounds__(256) void gemm128(const uint16_t* __restrict__ A,
                                               const uint16_t* __restrict__ Bt,
                                               void* __restrict__ Cout,
                                               const float* __restrict__ bias,
                                               int K, int ldc) {
    __shared__ char lds[32768];
    char* ldsA = lds;
    char* ldsB = lds + 16384;
    int m0 = blockIdx.x * 128, n0 = blockIdx.y * 128;
    int t = threadIdx.x, lane = t & 63, w = t >> 6;
    int wr = w >> 1, wc = w & 1;
    int l15 = lane & 15, lh = lane >> 4;
    f32x4 acc[4][4] = {};
    for (int k0 = 0; k0 < K; k0 += 64) {
        __syncthreads();
        {
            int row = t >> 3, ch = t & 7;
            #pragma unroll
            for (int p = 0; p < 4; p++) {
                int r = row + 32 * p;
                bf16x8 va = *(const bf16x8*)(A + (size_t)(m0 + r) * K + k0 + ch * 8);
                *(bf16x8*)(ldsA + r * 128 + ((ch * 16) ^ ((r & 7) << 4))) = va;
                bf16x8 vb = *(const bf16x8*)(Bt + (size_t)(n0 + r) * K + k0 + ch * 8);
                *(bf16x8*)(ldsB + r * 128 + ((ch * 16) ^ ((r & 7) << 4))) = vb;
            }
        }
        __syncthreads();
        #pragma unroll
        for (int kk = 0; kk < 2; kk++) {
            bf16x8 a[4], b[4];
            #pragma unroll
            for (int mi = 0; mi < 4; mi++) {
                int m = wr * 64 + mi * 16 + l15;
                a[mi] = *(const bf16x8*)(ldsA + m * 128 + ((kk * 64 + lh * 16) ^ ((m & 7) << 4)));
            }
            #pragma unroll
            for (int ni = 0; ni < 4; ni++) {
                int n = wc * 64 + ni * 16 + l15;
                b[ni] = *(const bf16x8*)(ldsB + n * 128 + ((kk * 64 + lh * 16) ^ ((n & 7) << 4)));
            }
            #pragma unroll
            for (int mi = 0; mi < 4; mi++)
                #pragma unroll
                for (int ni = 0; ni < 4; ni++)
                    acc[mi][ni] = __builtin_amdgcn_mfma_f32_16x16x32_bf16(a[mi], b[ni], acc[mi][ni], 0, 0, 0);
        }
    }
    #pragma unroll
    for (int mi = 0; mi < 4; mi++)
        #pragma unroll
        for (int ni = 0; ni < 4; ni++)
            #pragma unroll
            for (int i = 0; i < 4; i++) {
                int m = m0 + wr * 64 + mi * 16 + lh * 4 + i;
                int n = n0 + wc * 64 + ni * 16 + l15;
                float v = acc[mi][ni][i];
                if constexpr (BF16_OUT) ((uint16_t*)Cout)[(size_t)m * ldc + n] = f2bf(v);
                else                    ((float*)Cout)[(size_t)m * ldc + n] = v + bias[n];
            }
}

// ---------------------------------------------------------------- flash attention: R12 + hoisted rel loads,
//   recomputed clamp bias (no persistent bias regs), single barrier per tile
__global__ __launch_bounds__(512, 4) void attn_kernel(const uint16_t* __restrict__ QKV,
                                                      const uint16_t* __restrict__ relb,
                                                      float* __restrict__ Opart,
                                                      float* __restrict__ mlpart) {
    __shared__ __align__(16) char lds[53248];   // [0:16K) Q then P(8x2K) | 2 x (K 8K + V^T 10K)
    char* ldsQ = lds;
    char* ldsKV = lds + 16384;

    // XCD-chunked bijective remap (512 blocks)
    int flat = blockIdx.x + 16 * (blockIdx.y + 8 * blockIdx.z);   // 512 blocks
    int x = (flat & 7) * 64 + (flat >> 3);
    int qb = x & 15, h = (x >> 4) & 7, z = x >> 7;
    int b = z >> 1, sp = z & 1;

    int t = threadIdx.x, lane = t & 63, w = t >> 6;
    int l15 = lane & 15, lh = lane >> 4;
    int row = t >> 3, ch = t & 7;
    int n0 = qb * 128;
    int kvbase = sp * KV_PER_SPLIT;
    size_t rowQ = (size_t)b * NSEQ + n0;

    int swzSrc = (ch * 16) ^ ((row & 7) << 4);   // pre-swizzled source byte offset within a 128B row

    // ---- Q tile 128x64 via global_load_lds (linear dest = swizzled layout via source permutation)
    #pragma unroll
    for (int p = 0; p < 2; p++) {
        int r = row + 64 * p;
        const char* gsrc = (const char*)(QKV + (rowQ + r) * QKV_N + h * 64)
                           + ((ch * 16) ^ ((r & 7) << 4));
        __builtin_amdgcn_global_load_lds(gsrc, ldsQ + p * 8192 + t * 16, 16, 0, 0);
    }

    // ---- V^T constant rows 64..79: row 64 = ones (l-column), 65..79 = zeros; both buffers
    {
        int buf = t >> 8, idx = t & 255;
        uint32_t val = (idx < 16) ? 0x3F803F80u : 0u;
        char* p = ldsKV + buf * 18432 + 8192 + 8192 + (idx >> 4) * 128 + (idx & 15) * 8;
        *(uint32_t*)(p) = val;
        *(uint32_t*)(p + 4) = val;
    }

    auto stage_k = [&](int tile) {   // one 16B DMA per thread into buf[tile&1], zero VGPR round-trip
        const char* gsrc = (const char*)(QKV + ((size_t)b * NSEQ + kvbase + tile * 64 + row) * QKV_N
                                         + 512 + h * 64) + swzSrc;
        __builtin_amdgcn_global_load_lds(gsrc, ldsKV + (tile & 1) * 18432 + t * 16, 16, 0, 0);
    };
    auto load_v = [&](int tile, bf16x8& vr) {
        vr = *(const bf16x8*)(QKV + ((size_t)b * NSEQ + kvbase + tile * 64 + row) * QKV_N
                              + 1024 + h * 64 + ch * 8);
    };
    auto scatter_v = [&](int tile, bf16x8& vr) {
        char* ldsV = ldsKV + (tile & 1) * 18432 + 8192;
        #pragma unroll
        for (int dd = 0; dd < 8; dd++) {
            int d = ch * 8 + dd;
            int s = dd ^ ch;          // (d&7) ^ ((d>>3)&7)
            *(uint16_t*)(ldsV + d * 128 + 2 * (row ^ (s << 3))) = (uint16_t)vr[dd];
        }
    };

    // prologue: tile 0 K (DMA) + V (regs->LDS)
    bf16x8 vr;
    stage_k(0);
    load_v(0, vr);
    scatter_v(0, vr);
    __syncthreads();                  // Q + K(0) DMA drained, V(0) visible

    bf16x8 qf[2];
    #pragma unroll
    for (int kk = 0; kk < 2; kk++) {
        int m = w * 16 + l15;
        qf[kk] = *(const bf16x8*)(ldsQ + m * 128 + ((kk * 64 + lh * 16) ^ ((m & 7) << 4)));
    }
    char* myP = ldsQ + w * 2048;      // P overlays dead Q region (per-wave 2KB)

    f32x4 oacc[5] = {};               // [0..3] = O cols, [4] = l-column (col 64)
    float mrow[4];
    #pragma unroll
    for (int i = 0; i < 4; i++) mrow[i] = -INFINITY;

    // diagonal-extraction constants
    int exAddr[4];
    #pragma unroll
    for (int i = 0; i < 4; i++)
        exAddr[i] = (((lane & 48) | ((lh * 4 + i + 15 - l15) & 15)) << 2);

    const int NT = KV_PER_SPLIT / 64;   // 16

    #pragma unroll 1
    for (int tt = 0; tt < NT; ++tt) {
        char* ldsK = ldsKV + (tt & 1) * 18432;
        char* ldsV = ldsK + 8192;
        if (tt > 0) __syncthreads();               // tile tt K (DMA drained) + V visible
        bool pf = (tt + 1 < NT);
        if (pf) {
            stage_k(tt + 1);                       // DMA into buf^1 (drained at next barrier)
            load_v(tt + 1, vr);                    // global -> regs (consumed by scatter at body end)
        }

        int nk = n0 + w * 16 - (kvbase + tt * 64); // wave-uniform
        bool fullLo = (nk <= -527), fullHi = (nk >= 575);
        bool clamped = fullLo || fullHi;

        // rel B-frags issued BEFORE QK^T so its ~400cy of MFMA covers the L2 latency
        bf16x8 rfr[5][2];
        if (clamped) {
            const uint16_t* rp = relb + (fullLo ? 0 : 1024 * 64) + lh * 8;
            rfr[0][0] = *(const bf16x8*)(rp);
            rfr[0][1] = *(const bf16x8*)(rp + 32);
        } else {
            int dlo = nk - 63;
            #pragma unroll
            for (int f = 0; f < 5; f++) {
                int d = dlo + f * 16 + l15;
                d = d < -512 ? -512 : (d > 512 ? 512 : d);
                const uint16_t* rp = relb + (d + 512) * 64 + lh * 8;
                rfr[f][0] = *(const bf16x8*)(rp);
                rfr[f][1] = *(const bf16x8*)(rp + 32);
            }
        }

        // S = Q K^T
        f32x4 sacc[4] = {};
        __builtin_amdgcn_s_setprio(1);
        #pragma unroll
        for (int kk = 0; kk < 2; kk++)
            #pragma unroll
            for (int nf = 0; nf < 4; nf++) {
                int n = nf * 16 + l15;
                bf16x8 kfv = *(const bf16x8*)(ldsK + n * 128 + ((kk * 64 + lh * 16) ^ ((n & 7) << 4)));
                sacc[nf] = __builtin_amdgcn_mfma_f32_16x16x32_bf16(qf[kk], kfv, sacc[nf], 0, 0, 0);
            }
        __builtin_amdgcn_s_setprio(0);

        if (clamped) {
            // column-constant bias recomputed (2 MFMA, loads covered by QK^T)
            f32x4 bc = {};
            bc = __builtin_amdgcn_mfma_f32_16x16x32_bf16(qf[0], rfr[0][0], bc, 0, 0, 0);
            bc = __builtin_amdgcn_mfma_f32_16x16x32_bf16(qf[1], rfr[0][1], bc, 0, 0, 0);
            #pragma unroll
            for (int nf = 0; nf < 4; nf++)
                #pragma unroll
                for (int i = 0; i < 4; i++)
                    sacc[nf][i] += bc[i];
        } else {
            // rect MFMA (rfr already resident)
            f32x4 rect[5] = {};
            __builtin_amdgcn_s_setprio(1);
            #pragma unroll
            for (int f = 0; f < 5; f++) {
                rect[f] = __builtin_amdgcn_mfma_f32_16x16x32_bf16(qf[0], rfr[f][0], rect[f], 0, 0, 0);
                rect[f] = __builtin_amdgcn_mfma_f32_16x16x32_bf16(qf[1], rfr[f][1], rect[f], 0, 0, 0);
            }
            __builtin_amdgcn_s_setprio(0);
            // diagonal extraction: sacc[nf][i] += rect(r=lh*4+i, c=r+63-(16nf+l15))
            #pragma unroll
            for (int i = 0; i < 4; i++) {
                bool hi = (l15 < lh * 4 + i);
                #pragma unroll
                for (int nf = 0; nf < 4; nf++) {
                    float v = hi ? rect[4 - nf][i] : rect[3 - nf][i];
                    union { float f; int s; } un{v};
                    un.s = __builtin_amdgcn_ds_bpermute(exAddr[i], un.s);
                    sacc[nf][i] += un.f;
                }
            }
        }

        // defer-max gate: zero cross-lane ops on the common path
        float lmax = sacc[0][0];
        #pragma unroll
        for (int nf = 0; nf < 4; nf++)
            #pragma unroll
            for (int i = 0; i < 4; i++) lmax = fmaxf(lmax, sacc[nf][i]);
        float mmin = fminf(fminf(mrow[0], mrow[1]), fminf(mrow[2], mrow[3]));
        if (!__all(lmax <= mmin + 64.0f)) {   // rare: accurate row maxes + rescale
            #pragma unroll
            for (int i = 0; i < 4; i++) {
                float mx = fmaxf(fmaxf(sacc[0][i], sacc[1][i]), fmaxf(sacc[2][i], sacc[3][i]));
                mx = fmaxf(mx, __shfl_xor(mx, 1));
                mx = fmaxf(mx, __shfl_xor(mx, 2));
                mx = fmaxf(mx, __shfl_xor(mx, 4));
                mx = fmaxf(mx, __shfl_xor(mx, 8));
                float mnew = fmaxf(mrow[i], mx);
                float alpha = exp2f((mrow[i] - mnew) * SCALE_LOG2E);
                mrow[i] = mnew;
                #pragma unroll
                for (int nf = 0; nf < 5; nf++) oacc[nf][i] *= alpha;
            }
        }

        // P = exp2((S - m)*c) -> bf16 (cvt_pk RTNE) -> LDS
        #pragma unroll
        for (int i = 0; i < 4; i++) {
            int r = lh * 4 + i;
            int rsw = (r & 7) << 4;
            #pragma unroll
            for (int nf = 0; nf < 4; nf++) {
                float p = exp2f((sacc[nf][i] - mrow[i]) * SCALE_LOG2E);
                uint32_t pb;
                asm("v_cvt_pk_bf16_f32 %0, %1, %2" : "=v"(pb) : "v"(p), "v"(p));
                *(uint16_t*)(myP + r * 128 + (((nf * 16 + l15) * 2) ^ rsw)) = (uint16_t)pb;
            }
        }

        asm volatile("s_waitcnt lgkmcnt(0)" ::: "memory");
        __builtin_amdgcn_sched_barrier(0);
        __builtin_amdgcn_s_setprio(1);
        #pragma unroll
        for (int kk = 0; kk < 2; kk++) {
            bf16x8 pa = *(const bf16x8*)(myP + l15 * 128 + ((kk * 64 + lh * 16) ^ ((l15 & 7) << 4)));
            #pragma unroll
            for (int nf = 0; nf < 5; nf++) {      // nf==4: ones row -> l
                int d = nf * 16 + l15;
                int sd = (d & 7) ^ ((d >> 3) & 7);
                bf16x8 vb = *(const bf16x8*)(ldsV + d * 128 + 16 * ((kk * 4 + lh) ^ sd));
                oacc[nf] = __builtin_amdgcn_mfma_f32_16x16x32_bf16(pa, vb, oacc[nf], 0, 0, 0);
            }
        }
        __builtin_amdgcn_s_setprio(0);

        if (pf) scatter_v(tt + 1, vr);            // V regs -> buf^1 (all waves past top-tt barrier
                                                  // => body tt-1 reads of buf^1 complete)
    }

    // epilogue: unnormalized partial O (f32) + m/l per row (l lives in oacc[4], col 64 -> l15==0)
    size_t rbase = ((size_t)(sp * BATCH + b) * HEADS + h) * NSEQ;
    #pragma unroll
    for (int nf = 0; nf < 4; nf++)
        #pragma unroll
        for (int i = 0; i < 4; i++) {
            int r = n0 + w * 16 + lh * 4 + i;
            Opart[(rbase + r) * 64 + nf * 16 + l15] = oacc[nf][i];
        }
    if (l15 == 0) {
        #pragma unroll
        for (int i = 0; i < 4; i++) {
            int r = n0 + w * 16 + lh * 4 + i;
            mlpart[(rbase + r) * 2]     = mrow[i];
            mlpart[(rbase + r) * 2 + 1] = oacc[4][i];
        }
    }
}

// ---------------------------------------------------------------- combine the 2 KV-splits
__global__ __launch_bounds__(256) void combine_kernel(const float* __restrict__ Opart,
                                                      const float* __restrict__ mlpart,
                                                      uint16_t* __restrict__ attO) {
    int lane = threadIdx.x & 63;
    int R = blockIdx.x * 4 + (threadIdx.x >> 6);   // [0, 32768): (b*8+h)*2048 + n
    const int SPSTRIDE = BATCH * HEADS * NSEQ;     // 32768
    float m1 = mlpart[(size_t)R * 2], l1 = mlpart[(size_t)R * 2 + 1];
    float m2 = mlpart[((size_t)SPSTRIDE + R) * 2], l2 = mlpart[((size_t)SPSTRIDE + R) * 2 + 1];
    float M = fmaxf(m1, m2);
    float w1 = exp2f((m1 - M) * SCALE_LOG2E);
    float w2 = exp2f((m2 - M) * SCALE_LOG2E);
    float Linv = 1.f / (l1 * w1 + l2 * w2);
    float o1 = Opart[(size_t)R * 64 + lane];
    float o2 = Opart[((size_t)SPSTRIDE + R) * 64 + lane];
    float o = (o1 * w1 + o2 * w2) * Linv;
    int bh = R >> 11, n = R & 2047;
    int b = bh >> 3, hh = bh & 7;
    attO[((size_t)(b * NSEQ + n)) * DIM + hh * 64 + lane] = f2bf(o);
}

// ---------------------------------------------------------------- launch
extern "C" void kernel_launch(void* const* d_in, const int* in_sizes, int n_in,
                              void* d_out, int out_size, void* d_ws, size_t ws_size,
                              hipStream_t stream) {
    const float* x   = (const float*)d_in[0];
    const float* Wq  = (const float*)d_in[1];
    const float* Wkv = (const float*)d_in[2];
    const float* Wo  = (const float*)d_in[3];
    const float* bo  = (const float*)d_in[4];
    const float* rel = (const float*)d_in[5];
    char* ws = (char*)d_ws;
    // persistent
    float*    mlp    = (float*)(ws);                    // 2*32768*2*4  = 524,288
    uint16_t* Wo_t   = (uint16_t*)(ws + 524288);        // 512*512*2    = 524,288
    uint16_t* relb   = (uint16_t*)(ws + 1048576);       // 1088*64*2    = 139,264
    uint16_t* attO   = (uint16_t*)(ws + 1310720);       // 4096*512*2   = 4,194,304
    uint16_t* QKV    = (uint16_t*)(ws + 5505024);       // 4096*1536*2  = 12,582,912
    float*    Opart  = (float*)(ws + 18087936);         // 2*32768*64*4 = 16,777,216 (end 34,865,152)
    // transient prep buffers overlaid into Opart region (dead before attn writes Opart)
    uint16_t* Xb     = (uint16_t*)(ws + 18087936);      // 4096*512*2   = 4,194,304
    uint16_t* Wqkv_t = (uint16_t*)(ws + 22282240);      // 1536*512*2   = 1,572,864

    prep_all<<<3072, 256, 0, stream>>>(x, rel, Wq, Wkv, Wo, Xb, relb, Wqkv_t, Wo_t);
    gemm128<true><<<dim3(32, 12), 256, 0, stream>>>(Xb, Wqkv_t, QKV, nullptr, 512, QKV_N);
    attn_kernel<<<dim3(16, 8, 4), 512, 0, stream>>>(QKV, relb, Opart, mlp);
    combine_kernel<<<8192, 256, 0, stream>>>(Opart, mlp, attO);
    gemm128<false><<<dim3(32, 4), 256, 0, stream>>>(attO, Wo_t, (float*)d_out, bo, 512, DIM);
}

// Round 14
// 183.939 us; speedup vs baseline: 1.1852x; 1.1852x over previous
//
#include <hip/hip_runtime.h>
#include <hip/hip_bf16.h>
#include <stdint.h>

#define HEADS 8
#define DHEAD 64
#define DIM 512
#define NSEQ 2048
#define BATCH 2
#define NROWS (BATCH * NSEQ)      // 4096
#define QKV_N 1536
#define REL_ROWS 1025
#define REL_PITCH_ROWS 1088
#define NSPLIT 2
#define KV_PER_SPLIT (NSEQ / NSPLIT)   // 1024

static constexpr float SCALE_LOG2E = 0.125f * 1.4426950408889634f;  // SCALE * log2(e)

typedef __attribute__((ext_vector_type(8))) short bf16x8;   // 8 bf16 (4 VGPRs)
typedef __attribute__((ext_vector_type(4))) float f32x4;

__device__ __forceinline__ uint16_t f2bf(float f) {
    union { float f; uint32_t u; } v{f};
    uint32_t r = (v.u + 0x7FFFu + ((v.u >> 16) & 1u)) >> 16;
    return (uint16_t)r;
}

// ---------------------------------------------------------------- prep (merged): x->bf16, rel->bf16, W transposes
__global__ void prep_all(const float* __restrict__ x, const float* __restrict__ rel,
                         const float* __restrict__ Wq, const float* __restrict__ Wkv,
                         const float* __restrict__ Wo,
                         uint16_t* __restrict__ xb, uint16_t* __restrict__ relb,
                         uint16_t* __restrict__ Wqkv_t, uint16_t* __restrict__ Wo_t) {
    if (blockIdx.x < 2048) {
        int total = NROWS * DIM + REL_PITCH_ROWS * DHEAD;
        for (int idx = blockIdx.x * blockDim.x + threadIdx.x; idx < total; idx += 2048 * blockDim.x) {
            if (idx < NROWS * DIM) {
                xb[idx] = f2bf(x[idx]);
            } else {
                int i2 = idx - NROWS * DIM;
                relb[i2] = (i2 < REL_ROWS * DHEAD) ? f2bf(rel[i2]) : (uint16_t)0;
            }
        }
        return;
    }
    __shared__ float tile[32][33];
    int bid = blockIdx.x - 2048;
    const float* src; uint16_t* dst; int J, ti, tj;
    if (bid < 256)      { src = Wq;  dst = Wqkv_t;             J = 512;  ti = bid >> 4;        tj = bid & 15; }
    else if (bid < 768) { int b = bid - 256; src = Wkv; dst = Wqkv_t + 512 * 512; J = 1024; ti = b >> 5; tj = b & 31; }
    else                { int b = bid - 768; src = Wo;  dst = Wo_t;   J = 512;  ti = b >> 4;        tj = b & 15; }
    int tx = threadIdx.x & 31, ty = threadIdx.x >> 5;
    int k0 = ti * 32, j0 = tj * 32;
    #pragma unroll
    for (int i = 0; i < 4; i++) tile[ty + 8 * i][tx] = src[(size_t)(k0 + ty + 8 * i) * J + j0 + tx];
    __syncthreads();
    #pragma unroll
    for (int i = 0; i < 4; i++) dst[(size_t)(j0 + ty + 8 * i) * 512 + k0 + tx] = f2bf(tile[tx][ty + 8 * i]);
}

// ---------------------------------------------------------------- 128x128 MFMA GEMM: C = A[M,K] * Bt[N,K]^T
template <bool BF16_OUT>
__global__ __launch_bounds__(256) void gemm128(const uint16_t* __restrict__ A,
                                               const uint16_t* __restrict__ Bt,
                                               void* __restrict__ Cout,
                                               const float* __restrict__ bias,
                                               int K, int ldc) {
    __shared__ char lds[32768];
    char* ldsA = lds;
    char* ldsB = lds + 16384;
    int m0 = blockIdx.x * 128, n0 = blockIdx.y * 128;
    int t = threadIdx.x, lane = t & 63, w = t >> 6;
    int wr = w >> 1, wc = w & 1;
    int l15 = lane & 15, lh = lane >> 4;
    f32x4 acc[4][4] = {};
    for (int k0 = 0; k0 < K; k0 += 64) {
        __syncthreads();
        {
            int row = t >> 3, ch = t & 7;
            #pragma unroll
            for (int p = 0; p < 4; p++) {
                int r = row + 32 * p;
                bf16x8 va = *(const bf16x8*)(A + (size_t)(m0 + r) * K + k0 + ch * 8);
                *(bf16x8*)(ldsA + r * 128 + ((ch * 16) ^ ((r & 7) << 4))) = va;
                bf16x8 vb = *(const bf16x8*)(Bt + (size_t)(n0 + r) * K + k0 + ch * 8);
                *(bf16x8*)(ldsB + r * 128 + ((ch * 16) ^ ((r & 7) << 4))) = vb;
            }
        }
        __syncthreads();
        #pragma unroll
        for (int kk = 0; kk < 2; kk++) {
            bf16x8 a[4], b[4];
            #pragma unroll
            for (int mi = 0; mi < 4; mi++) {
                int m = wr * 64 + mi * 16 + l15;
                a[mi] = *(const bf16x8*)(ldsA + m * 128 + ((kk * 64 + lh * 16) ^ ((m & 7) << 4)));
            }
            #pragma unroll
            for (int ni = 0; ni < 4; ni++) {
                int n = wc * 64 + ni * 16 + l15;
                b[ni] = *(const bf16x8*)(ldsB + n * 128 + ((kk * 64 + lh * 16) ^ ((n & 7) << 4)));
            }
            #pragma unroll
            for (int mi = 0; mi < 4; mi++)
                #pragma unroll
                for (int ni = 0; ni < 4; ni++)
                    acc[mi][ni] = __builtin_amdgcn_mfma_f32_16x16x32_bf16(a[mi], b[ni], acc[mi][ni], 0, 0, 0);
        }
    }
    #pragma unroll
    for (int mi = 0; mi < 4; mi++)
        #pragma unroll
        for (int ni = 0; ni < 4; ni++)
            #pragma unroll
            for (int i = 0; i < 4; i++) {
                int m = m0 + wr * 64 + mi * 16 + lh * 4 + i;
                int n = n0 + wc * 64 + ni * 16 + l15;
                float v = acc[mi][ni][i];
                if constexpr (BF16_OUT) ((uint16_t*)Cout)[(size_t)m * ldc + n] = f2bf(v);
                else                    ((float*)Cout)[(size_t)m * ldc + n] = v + bias[n];
            }
}

// ---------------------------------------------------------------- flash attention: 4 independent 4-wave groups/CU,
//   QBLK=64, single-buffer K/V, DMA K/Q staging, R11 bias machinery (2-deep rfr, persistent clamp bias)
__global__ __launch_bounds__(256, 4) void attn_kernel(const uint16_t* __restrict__ QKV,
                                                      const uint16_t* __restrict__ relb,
                                                      float* __restrict__ Opart,
                                                      float* __restrict__ mlpart) {
    __shared__ __align__(16) char lds[26624];
    char* ldsQ = lds;            // 8 KB: Q (DMA, swizzled-by-source) -> P (4 waves x 2 KB)
    char* ldsK = lds + 8192;     // 8 KB [64][128B] swz
    char* ldsV = lds + 16384;    // 10 KB [80][128B]: rows 64..79 const (row 64 = ones)

    // XCD-chunked bijective remap (1024 blocks, 128/XCD)
    int flat = blockIdx.x + 32 * (blockIdx.y + 8 * blockIdx.z);   // 1024 blocks
    int x = (flat & 7) * 128 + (flat >> 3);
    int qb = x & 31, h = (x >> 5) & 7, z = x >> 8;
    int b = z >> 1, sp = z & 1;

    int t = threadIdx.x, lane = t & 63, w = t >> 6;
    int l15 = lane & 15, lh = lane >> 4;
    int r4 = t >> 2, q4 = t & 3;      // V staging: row 0..63, 32B col-chunk
    int n0 = qb * 64;
    int kvbase = sp * KV_PER_SPLIT;

    // ---- Q 64x64 via global_load_lds (linear dest; swizzle via pre-permuted source)
    #pragma unroll
    for (int p = 0; p < 2; p++) {
        int r = p * 32 + (t >> 3);
        const char* gsrc = (const char*)(QKV + ((size_t)b * NSEQ + n0 + r) * QKV_N + h * 64)
                           + (((t & 7) * 16) ^ ((r & 7) << 4));
        __builtin_amdgcn_global_load_lds(gsrc, ldsQ + p * 4096 + t * 16, 16, 0, 0);
    }

    // ---- V^T constant rows 64..79: row 64 = ones (l-column), 65..79 = zeros
    {
        uint32_t val = ((t >> 4) == 0) ? 0x3F803F80u : 0u;
        char* p = ldsV + 8192 + (t >> 4) * 128 + (t & 15) * 8;
        *(uint32_t*)(p) = val;
        *(uint32_t*)(p + 4) = val;
    }

    auto stage_k = [&](int tile) {   // two 16B DMAs per thread, zero VGPR round-trip
        #pragma unroll
        for (int p = 0; p < 2; p++) {
            int r = p * 32 + (t >> 3);
            const char* gsrc = (const char*)(QKV + ((size_t)b * NSEQ + kvbase + tile * 64 + r) * QKV_N
                                             + 512 + h * 64) + (((t & 7) * 16) ^ ((r & 7) << 4));
            __builtin_amdgcn_global_load_lds(gsrc, ldsK + p * 4096 + t * 16, 16, 0, 0);
        }
    };
    auto load_v = [&](int tile, bf16x8* vr) {
        size_t gro = ((size_t)b * NSEQ + kvbase + tile * 64 + r4) * QKV_N + 1024 + h * 64 + q4 * 16;
        vr[0] = *(const bf16x8*)(QKV + gro);
        vr[1] = *(const bf16x8*)(QKV + gro + 8);
    };
    auto scatter_v = [&](bf16x8* vr) {
        #pragma unroll
        for (int p = 0; p < 2; p++)
            #pragma unroll
            for (int dd = 0; dd < 8; dd++) {
                int d = q4 * 16 + p * 8 + dd;
                int s = (d & 7) ^ (d >> 3);
                *(uint16_t*)(ldsV + d * 128 + 2 * (r4 ^ (s << 3))) = (uint16_t)vr[p][dd];
            }
    };

    // prologue: tile 0 K (DMA) + V (regs -> LDS)
    bf16x8 vr[2];
    stage_k(0);
    load_v(0, vr);
    scatter_v(vr);
    __syncthreads();                  // Q + K(0) DMA drained, V(0) visible

    bf16x8 qf[2];
    #pragma unroll
    for (int kk = 0; kk < 2; kk++) {
        int m = w * 16 + l15;
        qf[kk] = *(const bf16x8*)(ldsQ + m * 128 + ((kk * 64 + lh * 16) ^ ((m & 7) << 4)));
    }
    char* myP = ldsQ + w * 2048;      // P overlays this wave's own Q rows

    // ---- clamp-region bias columns (column-constant): 4 MFMA, once per wave ----
    f32x4 biasLo = {}, biasHi = {};
    {
        bf16x8 bl0 = *(const bf16x8*)(relb + lh * 8);
        bf16x8 bl1 = *(const bf16x8*)(relb + lh * 8 + 32);
        bf16x8 bh0 = *(const bf16x8*)(relb + 1024 * 64 + lh * 8);
        bf16x8 bh1 = *(const bf16x8*)(relb + 1024 * 64 + lh * 8 + 32);
        biasLo = __builtin_amdgcn_mfma_f32_16x16x32_bf16(qf[0], bl0, biasLo, 0, 0, 0);
        biasLo = __builtin_amdgcn_mfma_f32_16x16x32_bf16(qf[1], bl1, biasLo, 0, 0, 0);
        biasHi = __builtin_amdgcn_mfma_f32_16x16x32_bf16(qf[0], bh0, biasHi, 0, 0, 0);
        biasHi = __builtin_amdgcn_mfma_f32_16x16x32_bf16(qf[1], bh1, biasHi, 0, 0, 0);
    }

    f32x4 oacc[5] = {};               // [0..3] = O cols, [4] = l-column (col 64)
    float mrow[4];
    #pragma unroll
    for (int i = 0; i < 4; i++) mrow[i] = -INFINITY;

    // diagonal-extraction constants
    int exAddr[4];
    #pragma unroll
    for (int i = 0; i < 4; i++)
        exAddr[i] = (((lane & 48) | ((lh * 4 + i + 15 - l15) & 15)) << 2);

    const int NT = KV_PER_SPLIT / 64;   // 16

    #pragma unroll 1
    for (int tt = 0; tt < NT; ++tt) {
        if (tt > 0) __syncthreads();               // tile tt staged & visible
        bool pf = (tt + 1 < NT);
        if (pf) load_v(tt + 1, vr);                // global -> regs, consumed after bottom barrier

        int nk = n0 + w * 16 - (kvbase + tt * 64); // wave-uniform
        bool fullLo = (nk <= -527), fullHi = (nk >= 575);

        // S = Q K^T
        f32x4 sacc[4] = {};
        __builtin_amdgcn_s_setprio(1);
        #pragma unroll
        for (int kk = 0; kk < 2; kk++)
            #pragma unroll
            for (int nf = 0; nf < 4; nf++) {
                int n = nf * 16 + l15;
                bf16x8 kfv = *(const bf16x8*)(ldsK + n * 128 + ((kk * 64 + lh * 16) ^ ((n & 7) << 4)));
                sacc[nf] = __builtin_amdgcn_mfma_f32_16x16x32_bf16(qf[kk], kfv, sacc[nf], 0, 0, 0);
            }
        __builtin_amdgcn_s_setprio(0);

        if (fullLo || fullHi) {
            // fully clamped: bias column-constant — no rect, no loads, no bpermute
            f32x4 bc = fullLo ? biasLo : biasHi;
            #pragma unroll
            for (int nf = 0; nf < 4; nf++)
                #pragma unroll
                for (int i = 0; i < 4; i++)
                    sacc[nf][i] += bc[i];
        } else {
            // rect MFMA with 2-deep rfr pipeline (R11, spill-free: 2 sets = 16 VGPR)
            int dlo = nk - 63;
            bf16x8 rfr[2][2];
            {
                int d = dlo + l15;
                d = d < -512 ? -512 : (d > 512 ? 512 : d);
                const uint16_t* rp = relb + (d + 512) * 64 + lh * 8;
                rfr[0][0] = *(const bf16x8*)(rp);
                rfr[0][1] = *(const bf16x8*)(rp + 32);
            }
            f32x4 rect[5] = {};
            #pragma unroll
            for (int f = 0; f < 5; f++) {
                if (f + 1 < 5) {
                    int d = dlo + (f + 1) * 16 + l15;
                    d = d < -512 ? -512 : (d > 512 ? 512 : d);
                    const uint16_t* rp = relb + (d + 512) * 64 + lh * 8;
                    rfr[(f + 1) & 1][0] = *(const bf16x8*)(rp);
                    rfr[(f + 1) & 1][1] = *(const bf16x8*)(rp + 32);
                }
                rect[f] = __builtin_amdgcn_mfma_f32_16x16x32_bf16(qf[0], rfr[f & 1][0], rect[f], 0, 0, 0);
                rect[f] = __builtin_amdgcn_mfma_f32_16x16x32_bf16(qf[1], rfr[f & 1][1], rect[f], 0, 0, 0);
                __builtin_amdgcn_sched_barrier(0);     // pin pipeline: stops full-hoist of rfr loads
            }
            // diagonal extraction: sacc[nf][i] += rect(r=lh*4+i, c=r+63-(16nf+l15))
            #pragma unroll
            for (int i = 0; i < 4; i++) {
                bool hi = (l15 < lh * 4 + i);
                #pragma unroll
                for (int nf = 0; nf < 4; nf++) {
                    float v = hi ? rect[4 - nf][i] : rect[3 - nf][i];
                    union { float f; int s; } un{v};
                    un.s = __builtin_amdgcn_ds_bpermute(exAddr[i], un.s);
                    sacc[nf][i] += un.f;
                }
            }
        }

        // defer-max gate: zero cross-lane ops on the common path
        float lmax = sacc[0][0];
        #pragma unroll
        for (int nf = 0; nf < 4; nf++)
            #pragma unroll
            for (int i = 0; i < 4; i++) lmax = fmaxf(lmax, sacc[nf][i]);
        float mmin = fminf(fminf(mrow[0], mrow[1]), fminf(mrow[2], mrow[3]));
        if (!__all(lmax <= mmin + 64.0f)) {   // rare: accurate row maxes + rescale
            #pragma unroll
            for (int i = 0; i < 4; i++) {
                float mx = fmaxf(fmaxf(sacc[0][i], sacc[1][i]), fmaxf(sacc[2][i], sacc[3][i]));
                mx = fmaxf(mx, __shfl_xor(mx, 1));
                mx = fmaxf(mx, __shfl_xor(mx, 2));
                mx = fmaxf(mx, __shfl_xor(mx, 4));
                mx = fmaxf(mx, __shfl_xor(mx, 8));
                float mnew = fmaxf(mrow[i], mx);
                float alpha = exp2f((mrow[i] - mnew) * SCALE_LOG2E);
                mrow[i] = mnew;
                #pragma unroll
                for (int nf = 0; nf < 5; nf++) oacc[nf][i] *= alpha;
            }
        }

        // P = exp2((S - m)*c) -> bf16 (cvt_pk RTNE) -> LDS (own-wave region)
        #pragma unroll
        for (int i = 0; i < 4; i++) {
            int r = lh * 4 + i;
            int rsw = (r & 7) << 4;
            #pragma unroll
            for (int nf = 0; nf < 4; nf++) {
                float p = exp2f((sacc[nf][i] - mrow[i]) * SCALE_LOG2E);
                uint32_t pb;
                asm("v_cvt_pk_bf16_f32 %0, %1, %2" : "=v"(pb) : "v"(p), "v"(p));
                *(uint16_t*)(myP + r * 128 + (((nf * 16 + l15) * 2) ^ rsw)) = (uint16_t)pb;
            }
        }

        asm volatile("s_waitcnt lgkmcnt(0)" ::: "memory");
        __builtin_amdgcn_sched_barrier(0);
        __builtin_amdgcn_s_setprio(1);
        #pragma unroll
        for (int kk = 0; kk < 2; kk++) {
            bf16x8 pa = *(const bf16x8*)(myP + l15 * 128 + ((kk * 64 + lh * 16) ^ ((l15 & 7) << 4)));
            #pragma unroll
            for (int nf = 0; nf < 5; nf++) {      // nf==4: ones row -> l
                int d = nf * 16 + l15;
                int sd = (d & 7) ^ ((d >> 3) & 7);
                bf16x8 vb = *(const bf16x8*)(ldsV + d * 128 + 16 * ((kk * 4 + lh) ^ sd));
                oacc[nf] = __builtin_amdgcn_mfma_f32_16x16x32_bf16(pa, vb, oacc[nf], 0, 0, 0);
            }
        }
        __builtin_amdgcn_s_setprio(0);

        __syncthreads();                          // all reads of tile tt done
        if (pf) { stage_k(tt + 1); scatter_v(vr); }   // write tile tt+1 into the single buffer
    }

    // epilogue: unnormalized partial O (f32) + m/l per row (l lives in oacc[4], col 64 -> l15==0)
    size_t rbase = ((size_t)(sp * BATCH + b) * HEADS + h) * NSEQ;
    #pragma unroll
    for (int nf = 0; nf < 4; nf++)
        #pragma unroll
        for (int i = 0; i < 4; i++) {
            int r = n0 + w * 16 + lh * 4 + i;
            Opart[(rbase + r) * 64 + nf * 16 + l15] = oacc[nf][i];
        }
    if (l15 == 0) {
        #pragma unroll
        for (int i = 0; i < 4; i++) {
            int r = n0 + w * 16 + lh * 4 + i;
            mlpart[(rbase + r) * 2]     = mrow[i];
            mlpart[(rbase + r) * 2 + 1] = oacc[4][i];
        }
    }
}

// ---------------------------------------------------------------- combine the 2 KV-splits
__global__ __launch_bounds__(256) void combine_kernel(const float* __restrict__ Opart,
                                                      const float* __restrict__ mlpart,
                                                      uint16_t* __restrict__ attO) {
    int lane = threadIdx.x & 63;
    int R = blockIdx.x * 4 + (threadIdx.x >> 6);   // [0, 32768): (b*8+h)*2048 + n
    const int SPSTRIDE = BATCH * HEADS * NSEQ;     // 32768
    float m1 = mlpart[(size_t)R * 2], l1 = mlpart[(size_t)R * 2 + 1];
    float m2 = mlpart[((size_t)SPSTRIDE + R) * 2], l2 = mlpart[((size_t)SPSTRIDE + R) * 2 + 1];
    float M = fmaxf(m1, m2);
    float w1 = exp2f((m1 - M) * SCALE_LOG2E);
    float w2 = exp2f((m2 - M) * SCALE_LOG2E);
    float Linv = 1.f / (l1 * w1 + l2 * w2);
    float o1 = Opart[(size_t)R * 64 + lane];
    float o2 = Opart[((size_t)SPSTRIDE + R) * 64 + lane];
    float o = (o1 * w1 + o2 * w2) * Linv;
    int bh = R >> 11, n = R & 2047;
    int b = bh >> 3, hh = bh & 7;
    attO[((size_t)(b * NSEQ + n)) * DIM + hh * 64 + lane] = f2bf(o);
}

// ---------------------------------------------------------------- launch
extern "C" void kernel_launch(void* const* d_in, const int* in_sizes, int n_in,
                              void* d_out, int out_size, void* d_ws, size_t ws_size,
                              hipStream_t stream) {
    const float* x   = (const float*)d_in[0];
    const float* Wq  = (const float*)d_in[1];
    const float* Wkv = (const float*)d_in[2];
    const float* Wo  = (const float*)d_in[3];
    const float* bo  = (const float*)d_in[4];
    const float* rel = (const float*)d_in[5];
    char* ws = (char*)d_ws;
    // persistent
    float*    mlp    = (float*)(ws);                    // 2*32768*2*4  = 524,288
    uint16_t* Wo_t   = (uint16_t*)(ws + 524288);        // 512*512*2    = 524,288
    uint16_t* relb   = (uint16_t*)(ws + 1048576);       // 1088*64*2    = 139,264
    uint16_t* attO   = (uint16_t*)(ws + 1310720);       // 4096*512*2   = 4,194,304
    uint16_t* QKV    = (uint16_t*)(ws + 5505024);       // 4096*1536*2  = 12,582,912
    float*    Opart  = (float*)(ws + 18087936);         // 2*32768*64*4 = 16,777,216 (end 34,865,152)
    // transient prep buffers overlaid into Opart region (dead before attn writes Opart)
    uint16_t* Xb     = (uint16_t*)(ws + 18087936);      // 4096*512*2   = 4,194,304
    uint16_t* Wqkv_t = (uint16_t*)(ws + 22282240);      // 1536*512*2   = 1,572,864

    prep_all<<<3072, 256, 0, stream>>>(x, rel, Wq, Wkv, Wo, Xb, relb, Wqkv_t, Wo_t);
    gemm128<true><<<dim3(32, 12), 256, 0, stream>>>(Xb, Wqkv_t, QKV, nullptr, 512, QKV_N);
    attn_kernel<<<dim3(32, 8, 4), 256, 0, stream>>>(QKV, relb, Opart, mlp);
    combine_kernel<<<8192, 256, 0, stream>>>(Opart, mlp, attO);
    gemm128<false><<<dim3(32, 4), 256, 0, stream>>>(attO, Wo_t, (float*)d_out, bo, 512, DIM);
}

// Round 15
// 129.599 us; speedup vs baseline: 1.6821x; 1.4193x over previous
//
#include <hip/hip_runtime.h>
#include <hip/hip_bf16.h>
#include <stdint.h>

#define HEADS 8
#define DHEAD 64
#define DIM 512
#define NSEQ 2048
#define BATCH 2
#define NROWS (BATCH * NSEQ)      // 4096
#define QKV_N 1536
#define REL_ROWS 1025
#define REL_PITCH_ROWS 1088
#define NSPLIT 2
#define KV_PER_SPLIT (NSEQ / NSPLIT)   // 1024

static constexpr float SCALE_LOG2E = 0.125f * 1.4426950408889634f;  // SCALE * log2(e)

typedef __attribute__((ext_vector_type(8))) short bf16x8;   // 8 bf16 (4 VGPRs)
typedef __attribute__((ext_vector_type(4))) float f32x4;

__device__ __forceinline__ uint16_t f2bf(float f) {
    union { float f; uint32_t u; } v{f};
    uint32_t r = (v.u + 0x7FFFu + ((v.u >> 16) & 1u)) >> 16;
    return (uint16_t)r;
}

// ---------------------------------------------------------------- prep (merged): x->bf16, rel->bf16, W transposes
__global__ void prep_all(const float* __restrict__ x, const float* __restrict__ rel,
                         const float* __restrict__ Wq, const float* __restrict__ Wkv,
                         const float* __restrict__ Wo,
                         uint16_t* __restrict__ xb, uint16_t* __restrict__ relb,
                         uint16_t* __restrict__ Wqkv_t, uint16_t* __restrict__ Wo_t) {
    if (blockIdx.x < 2048) {
        int total = NROWS * DIM + REL_PITCH_ROWS * DHEAD;
        for (int idx = blockIdx.x * blockDim.x + threadIdx.x; idx < total; idx += 2048 * blockDim.x) {
            if (idx < NROWS * DIM) {
                xb[idx] = f2bf(x[idx]);
            } else {
                int i2 = idx - NROWS * DIM;
                relb[i2] = (i2 < REL_ROWS * DHEAD) ? f2bf(rel[i2]) : (uint16_t)0;
            }
        }
        return;
    }
    __shared__ float tile[32][33];
    int bid = blockIdx.x - 2048;
    const float* src; uint16_t* dst; int J, ti, tj;
    if (bid < 256)      { src = Wq;  dst = Wqkv_t;             J = 512;  ti = bid >> 4;        tj = bid & 15; }
    else if (bid < 768) { int b = bid - 256; src = Wkv; dst = Wqkv_t + 512 * 512; J = 1024; ti = b >> 5; tj = b & 31; }
    else                { int b = bid - 768; src = Wo;  dst = Wo_t;   J = 512;  ti = b >> 4;        tj = b & 15; }
    int tx = threadIdx.x & 31, ty = threadIdx.x >> 5;
    int k0 = ti * 32, j0 = tj * 32;
    #pragma unroll
    for (int i = 0; i < 4; i++) tile[ty + 8 * i][tx] = src[(size_t)(k0 + ty + 8 * i) * J + j0 + tx];
    __syncthreads();
    #pragma unroll
    for (int i = 0; i < 4; i++) dst[(size_t)(j0 + ty + 8 * i) * 512 + k0 + tx] = f2bf(tile[tx][ty + 8 * i]);
}

// ---------------------------------------------------------------- 128x128 MFMA GEMM: C = A[M,K] * Bt[N,K]^T
template <bool BF16_OUT>
__global__ __launch_bounds__(256) void gemm128(const uint16_t* __restrict__ A,
                                               const uint16_t* __restrict__ Bt,
                                               void* __restrict__ Cout,
                                               const float* __restrict__ bias,
                                               int K, int ldc) {
    __shared__ char lds[32768];
    char* ldsA = lds;
    char* ldsB = lds + 16384;
    int m0 = blockIdx.x * 128, n0 = blockIdx.y * 128;
    int t = threadIdx.x, lane = t & 63, w = t >> 6;
    int wr = w >> 1, wc = w & 1;
    int l15 = lane & 15, lh = lane >> 4;
    f32x4 acc[4][4] = {};
    for (int k0 = 0; k0 < K; k0 += 64) {
        __syncthreads();
        {
            int row = t >> 3, ch = t & 7;
            #pragma unroll
            for (int p = 0; p < 4; p++) {
                int r = row + 32 * p;
                bf16x8 va = *(const bf16x8*)(A + (size_t)(m0 + r) * K + k0 + ch * 8);
                *(bf16x8*)(ldsA + r * 128 + ((ch * 16) ^ ((r & 7) << 4))) = va;
                bf16x8 vb = *(const bf16x8*)(Bt + (size_t)(n0 + r) * K + k0 + ch * 8);
                *(bf16x8*)(ldsB + r * 128 + ((ch * 16) ^ ((r & 7) << 4))) = vb;
            }
        }
        __syncthreads();
        #pragma unroll
        for (int kk = 0; kk < 2; kk++) {
            bf16x8 a[4], b[4];
            #pragma unroll
            for (int mi = 0; mi < 4; mi++) {
                int m = wr * 64 + mi * 16 + l15;
                a[mi] = *(const bf16x8*)(ldsA + m * 128 + ((kk * 64 + lh * 16) ^ ((m & 7) << 4)));
            }
            #pragma unroll
            for (int ni = 0; ni < 4; ni++) {
                int n = wc * 64 + ni * 16 + l15;
                b[ni] = *(const bf16x8*)(ldsB + n * 128 + ((kk * 64 + lh * 16) ^ ((n & 7) << 4)));
            }
            #pragma unroll
            for (int mi = 0; mi < 4; mi++)
                #pragma unroll
                for (int ni = 0; ni < 4; ni++)
                    acc[mi][ni] = __builtin_amdgcn_mfma_f32_16x16x32_bf16(a[mi], b[ni], acc[mi][ni], 0, 0, 0);
        }
    }
    #pragma unroll
    for (int mi = 0; mi < 4; mi++)
        #pragma unroll
        for (int ni = 0; ni < 4; ni++)
            #pragma unroll
            for (int i = 0; i < 4; i++) {
                int m = m0 + wr * 64 + mi * 16 + lh * 4 + i;
                int n = n0 + wc * 64 + ni * 16 + l15;
                float v = acc[mi][ni][i];
                if constexpr (BF16_OUT) ((uint16_t*)Cout)[(size_t)m * ldc + n] = f2bf(v);
                else                    ((float*)Cout)[(size_t)m * ldc + n] = v + bias[n];
            }
}

// ---------------------------------------------------------------- flash attention (R11 exact): spill-free
//   rect bias (2-deep rfr pipeline) + clamp-region shortcut (column-constant bias)
__global__ __launch_bounds__(512, 4) void attn_kernel(const uint16_t* __restrict__ QKV,
                                                      const uint16_t* __restrict__ relb,
                                                      float* __restrict__ Opart,
                                                      float* __restrict__ mlpart) {
    __shared__ char lds[53248];   // [0:16K) Q then P(8x2K) | 2 x (K 8K + V^T 10K)
    char* ldsQ = lds;
    char* ldsKV = lds + 16384;

    // XCD-chunked bijective remap (512 blocks)
    int flat = blockIdx.x + 16 * (blockIdx.y + 8 * blockIdx.z);   // 512 blocks
    int x = (flat & 7) * 64 + (flat >> 3);
    int qb = x & 15, h = (x >> 4) & 7, z = x >> 7;
    int b = z >> 1, sp = z & 1;

    int t = threadIdx.x, lane = t & 63, w = t >> 6;
    int l15 = lane & 15, lh = lane >> 4;
    int row = t >> 3, ch = t & 7;
    int n0 = qb * 128;
    int kvbase = sp * KV_PER_SPLIT;
    size_t rowQ = (size_t)b * NSEQ + n0;

    // ---- V^T constant rows 64..79: row 64 = ones (l-column), 65..79 = zeros; both buffers
    {
        int buf = t >> 8, idx = t & 255;
        uint32_t val = (idx < 16) ? 0x3F803F80u : 0u;
        char* p = ldsKV + buf * 18432 + 8192 + 8192 + (idx >> 4) * 128 + (idx & 15) * 8;
        *(uint32_t*)(p) = val;
        *(uint32_t*)(p + 4) = val;
    }

    // ---- stage Q tile 128x64 (swizzled) ----
    #pragma unroll
    for (int p = 0; p < 2; p++) {
        int r = row + 64 * p;
        bf16x8 v = *(const bf16x8*)(QKV + (rowQ + r) * QKV_N + h * 64 + ch * 8);
        *(bf16x8*)(ldsQ + r * 128 + ((ch * 16) ^ ((r & 7) << 4))) = v;
    }
    __syncthreads();
    bf16x8 qf[2];
    #pragma unroll
    for (int kk = 0; kk < 2; kk++) {
        int m = w * 16 + l15;
        qf[kk] = *(const bf16x8*)(ldsQ + m * 128 + ((kk * 64 + lh * 16) ^ ((m & 7) << 4)));
    }
    char* myP = ldsQ + w * 2048;      // P overlays dead Q region (per-wave 2KB)

    // ---- clamp-region bias columns (column-constant): 4 MFMA, once per wave ----
    f32x4 biasLo = {}, biasHi = {};
    {
        bf16x8 bl0 = *(const bf16x8*)(relb + lh * 8);
        bf16x8 bl1 = *(const bf16x8*)(relb + lh * 8 + 32);
        bf16x8 bh0 = *(const bf16x8*)(relb + 1024 * 64 + lh * 8);
        bf16x8 bh1 = *(const bf16x8*)(relb + 1024 * 64 + lh * 8 + 32);
        biasLo = __builtin_amdgcn_mfma_f32_16x16x32_bf16(qf[0], bl0, biasLo, 0, 0, 0);
        biasLo = __builtin_amdgcn_mfma_f32_16x16x32_bf16(qf[1], bl1, biasLo, 0, 0, 0);
        biasHi = __builtin_amdgcn_mfma_f32_16x16x32_bf16(qf[0], bh0, biasHi, 0, 0, 0);
        biasHi = __builtin_amdgcn_mfma_f32_16x16x32_bf16(qf[1], bh1, biasHi, 0, 0, 0);
    }

    f32x4 oacc[5] = {};               // [0..3] = O cols, [4] = l-column (col 64)
    float mrow[4];
    #pragma unroll
    for (int i = 0; i < 4; i++) mrow[i] = -INFINITY;

    // diagonal-extraction constants
    int exAddr[4];
    #pragma unroll
    for (int i = 0; i < 4; i++)
        exAddr[i] = (((lane & 48) | ((lh * 4 + i + 15 - l15) & 15)) << 2);

    auto load_kv = [&](int tile, bf16x8& kr, bf16x8& vr) {
        size_t gro = ((size_t)b * NSEQ + kvbase + tile * 64 + row) * QKV_N + h * 64 + ch * 8;
        kr = *(const bf16x8*)(QKV + gro + 512);
        vr = *(const bf16x8*)(QKV + gro + 1024);
    };
    auto scatter_kv = [&](int tile, bf16x8& kr, bf16x8& vr) {
        char* ldsK = ldsKV + (tile & 1) * 18432;
        char* ldsV = ldsK + 8192;
        *(bf16x8*)(ldsK + row * 128 + ((ch * 16) ^ ((row & 7) << 4))) = kr;
        #pragma unroll
        for (int dd = 0; dd < 8; dd++) {
            int d = ch * 8 + dd;
            int s = dd ^ ch;          // (d&7) ^ ((d>>3)&7)
            *(uint16_t*)(ldsV + d * 128 + 2 * (row ^ (s << 3))) = (uint16_t)vr[dd];
        }
    };

    const int NT = KV_PER_SPLIT / 64;   // 16
    bf16x8 kr, vr;
    load_kv(0, kr, vr);
    scatter_kv(0, kr, vr);

    #pragma unroll 1
    for (int tt = 0; tt < NT; ++tt) {
        char* ldsK = ldsKV + (tt & 1) * 18432;
        char* ldsV = ldsK + 8192;
        __syncthreads();                               // tile tt K/V visible
        bool pf = (tt + 1 < NT);
        if (pf) load_kv(tt + 1, kr, vr);               // HBM prefetch for next tile

        int nk = n0 + w * 16 - (kvbase + tt * 64);     // wave-uniform
        bool fullLo = (nk <= -527), fullHi = (nk >= 575);

        // S = Q K^T
        f32x4 sacc[4] = {};
        __builtin_amdgcn_s_setprio(1);
        #pragma unroll
        for (int kk = 0; kk < 2; kk++)
            #pragma unroll
            for (int nf = 0; nf < 4; nf++) {
                int n = nf * 16 + l15;
                bf16x8 kfv = *(const bf16x8*)(ldsK + n * 128 + ((kk * 64 + lh * 16) ^ ((n & 7) << 4)));
                sacc[nf] = __builtin_amdgcn_mfma_f32_16x16x32_bf16(qf[kk], kfv, sacc[nf], 0, 0, 0);
            }
        __builtin_amdgcn_s_setprio(0);

        if (fullLo || fullHi) {
            // fully clamped: bias column-constant — no rect, no loads, no bpermute
            f32x4 bc = fullLo ? biasLo : biasHi;
            #pragma unroll
            for (int nf = 0; nf < 4; nf++)
                #pragma unroll
                for (int i = 0; i < 4; i++)
                    sacc[nf][i] += bc[i];
        } else {
            // rect MFMA with 2-deep rfr pipeline (caps live B-frags at 2 sets = 16 VGPR)
            int dlo = nk - 63;
            bf16x8 rfr[2][2];
            {
                int d = dlo + l15;
                d = d < -512 ? -512 : (d > 512 ? 512 : d);
                const uint16_t* rp = relb + (d + 512) * 64 + lh * 8;
                rfr[0][0] = *(const bf16x8*)(rp);
                rfr[0][1] = *(const bf16x8*)(rp + 32);
            }
            f32x4 rect[5] = {};
            #pragma unroll
            for (int f = 0; f < 5; f++) {
                if (f + 1 < 5) {
                    int d = dlo + (f + 1) * 16 + l15;
                    d = d < -512 ? -512 : (d > 512 ? 512 : d);
                    const uint16_t* rp = relb + (d + 512) * 64 + lh * 8;
                    rfr[(f + 1) & 1][0] = *(const bf16x8*)(rp);
                    rfr[(f + 1) & 1][1] = *(const bf16x8*)(rp + 32);
                }
                rect[f] = __builtin_amdgcn_mfma_f32_16x16x32_bf16(qf[0], rfr[f & 1][0], rect[f], 0, 0, 0);
                rect[f] = __builtin_amdgcn_mfma_f32_16x16x32_bf16(qf[1], rfr[f & 1][1], rect[f], 0, 0, 0);
                __builtin_amdgcn_sched_barrier(0);     // pin pipeline: stops full-hoist of rfr loads
            }
            // diagonal extraction: sacc[nf][i] += rect(r=lh*4+i, c=r+63-(16nf+l15))
            #pragma unroll
            for (int i = 0; i < 4; i++) {
                bool hi = (l15 < lh * 4 + i);
                #pragma unroll
                for (int nf = 0; nf < 4; nf++) {
                    float v = hi ? rect[4 - nf][i] : rect[3 - nf][i];
                    union { float f; int s; } un{v};
                    un.s = __builtin_amdgcn_ds_bpermute(exAddr[i], un.s);
                    sacc[nf][i] += un.f;
                }
            }
        }

        // defer-max gate: zero cross-lane ops on the common path
        float lmax = sacc[0][0];
        #pragma unroll
        for (int nf = 0; nf < 4; nf++)
            #pragma unroll
            for (int i = 0; i < 4; i++) lmax = fmaxf(lmax, sacc[nf][i]);
        float mmin = fminf(fminf(mrow[0], mrow[1]), fminf(mrow[2], mrow[3]));
        if (!__all(lmax <= mmin + 64.0f)) {   // rare: accurate row maxes + rescale
            #pragma unroll
            for (int i = 0; i < 4; i++) {
                float mx = fmaxf(fmaxf(sacc[0][i], sacc[1][i]), fmaxf(sacc[2][i], sacc[3][i]));
                mx = fmaxf(mx, __shfl_xor(mx, 1));
                mx = fmaxf(mx, __shfl_xor(mx, 2));
                mx = fmaxf(mx, __shfl_xor(mx, 4));
                mx = fmaxf(mx, __shfl_xor(mx, 8));
                float mnew = fmaxf(mrow[i], mx);
                float alpha = exp2f((mrow[i] - mnew) * SCALE_LOG2E);
                mrow[i] = mnew;
                #pragma unroll
                for (int nf = 0; nf < 5; nf++) oacc[nf][i] *= alpha;
            }
        }

        // P = exp2((S - m)*c) -> bf16 (cvt_pk RTNE) -> LDS
        #pragma unroll
        for (int i = 0; i < 4; i++) {
            int r = lh * 4 + i;
            int rsw = (r & 7) << 4;
            #pragma unroll
            for (int nf = 0; nf < 4; nf++) {
                float p = exp2f((sacc[nf][i] - mrow[i]) * SCALE_LOG2E);
                uint32_t pb;
                asm("v_cvt_pk_bf16_f32 %0, %1, %2" : "=v"(pb) : "v"(p), "v"(p));
                *(uint16_t*)(myP + r * 128 + (((nf * 16 + l15) * 2) ^ rsw)) = (uint16_t)pb;
            }
        }

        asm volatile("s_waitcnt lgkmcnt(0)" ::: "memory");
        __builtin_amdgcn_sched_barrier(0);
        __builtin_amdgcn_s_setprio(1);
        #pragma unroll
        for (int kk = 0; kk < 2; kk++) {
            bf16x8 pa = *(const bf16x8*)(myP + l15 * 128 + ((kk * 64 + lh * 16) ^ ((l15 & 7) << 4)));
            #pragma unroll
            for (int nf = 0; nf < 5; nf++) {      // nf==4: ones row -> l
                int d = nf * 16 + l15;
                int sd = (d & 7) ^ ((d >> 3) & 7);
                bf16x8 vb = *(const bf16x8*)(ldsV + d * 128 + 16 * ((kk * 4 + lh) ^ sd));
                oacc[nf] = __builtin_amdgcn_mfma_f32_16x16x32_bf16(pa, vb, oacc[nf], 0, 0, 0);
            }
        }
        __builtin_amdgcn_s_setprio(0);

        if (pf) scatter_kv(tt + 1, kr, vr);       // into buf[(tt+1)&1]; dbuf -> single barrier/tile
    }

    // epilogue: unnormalized partial O (f32) + m/l per row (l lives in oacc[4], col 64 -> l15==0)
    size_t rbase = ((size_t)(sp * BATCH + b) * HEADS + h) * NSEQ;
    #pragma unroll
    for (int nf = 0; nf < 4; nf++)
        #pragma unroll
        for (int i = 0; i < 4; i++) {
            int r = n0 + w * 16 + lh * 4 + i;
            Opart[(rbase + r) * 64 + nf * 16 + l15] = oacc[nf][i];
        }
    if (l15 == 0) {
        #pragma unroll
        for (int i = 0; i < 4; i++) {
            int r = n0 + w * 16 + lh * 4 + i;
            mlpart[(rbase + r) * 2]     = mrow[i];
            mlpart[(rbase + r) * 2 + 1] = oacc[4][i];
        }
    }
}

// ---------------------------------------------------------------- combine the 2 KV-splits
__global__ __launch_bounds__(256) void combine_kernel(const float* __restrict__ Opart,
                                                      const float* __restrict__ mlpart,
                                                      uint16_t* __restrict__ attO) {
    int lane = threadIdx.x & 63;
    int R = blockIdx.x * 4 + (threadIdx.x >> 6);   // [0, 32768): (b*8+h)*2048 + n
    const int SPSTRIDE = BATCH * HEADS * NSEQ;     // 32768
    float m1 = mlpart[(size_t)R * 2], l1 = mlpart[(size_t)R * 2 + 1];
    float m2 = mlpart[((size_t)SPSTRIDE + R) * 2], l2 = mlpart[((size_t)SPSTRIDE + R) * 2 + 1];
    float M = fmaxf(m1, m2);
    float w1 = exp2f((m1 - M) * SCALE_LOG2E);
    float w2 = exp2f((m2 - M) * SCALE_LOG2E);
    float Linv = 1.f / (l1 * w1 + l2 * w2);
    float o1 = Opart[(size_t)R * 64 + lane];
    float o2 = Opart[((size_t)SPSTRIDE + R) * 64 + lane];
    float o = (o1 * w1 + o2 * w2) * Linv;
    int bh = R >> 11, n = R & 2047;
    int b = bh >> 3, hh = bh & 7;
    attO[((size_t)(b * NSEQ + n)) * DIM + hh * 64 + lane] = f2bf(o);
}

// ---------------------------------------------------------------- launch
extern "C" void kernel_launch(void* const* d_in, const int* in_sizes, int n_in,
                              void* d_out, int out_size, void* d_ws, size_t ws_size,
                              hipStream_t stream) {
    const float* x   = (const float*)d_in[0];
    const float* Wq  = (const float*)d_in[1];
    const float* Wkv = (const float*)d_in[2];
    const float* Wo  = (const float*)d_in[3];
    const float* bo  = (const float*)d_in[4];
    const float* rel = (const float*)d_in[5];
    char* ws = (char*)d_ws;
    // persistent
    float*    mlp    = (float*)(ws);                    // 2*32768*2*4  = 524,288
    uint16_t* Wo_t   = (uint16_t*)(ws + 524288);        // 512*512*2    = 524,288
    uint16_t* relb   = (uint16_t*)(ws + 1048576);       // 1088*64*2    = 139,264
    uint16_t* attO   = (uint16_t*)(ws + 1310720);       // 4096*512*2   = 4,194,304
    uint16_t* QKV    = (uint16_t*)(ws + 5505024);       // 4096*1536*2  = 12,582,912
    float*    Opart  = (float*)(ws + 18087936);         // 2*32768*64*4 = 16,777,216 (end 34,865,152)
    // transient prep buffers overlaid into Opart region (dead before attn writes Opart)
    uint16_t* Xb     = (uint16_t*)(ws + 18087936);      // 4096*512*2   = 4,194,304
    uint16_t* Wqkv_t = (uint16_t*)(ws + 22282240);      // 1536*512*2   = 1,572,864

    prep_all<<<3072, 256, 0, stream>>>(x, rel, Wq, Wkv, Wo, Xb, relb, Wqkv_t, Wo_t);
    gemm128<true><<<dim3(32, 12), 256, 0, stream>>>(Xb, Wqkv_t, QKV, nullptr, 512, QKV_N);
    attn_kernel<<<dim3(16, 8, 4), 512, 0, stream>>>(QKV, relb, Opart, mlp);
    combine_kernel<<<8192, 256, 0, stream>>>(Opart, mlp, attO);
    gemm128<false><<<dim3(32, 4), 256, 0, stream>>>(attO, Wo_t, (float*)d_out, bo, 512, DIM);
}